// Round 7
// baseline (217.928 us; speedup 1.0000x reference)
//
#include <hip/hip_runtime.h>
#include <hip/hip_bf16.h>
#include <math.h>

#define NHEADS 16
#define DKH 64
#define SEQ 2048
#define DMODEL 1024

typedef __attribute__((ext_vector_type(8))) short short8;
typedef __attribute__((ext_vector_type(4))) float f32x4;

// async global->LDS, 16B per lane. LDS dest = wave-uniform base + lane*16.
#define GLDS16(g, l)                                         \
  __builtin_amdgcn_global_load_lds(                          \
      (__attribute__((address_space(1))) void*)(void*)(g),   \
      (__attribute__((address_space(3))) void*)(l), 16, 0, 0)

__device__ __forceinline__ short f2bf(float f) {
  unsigned u = __float_as_uint(f);
  unsigned r = (u + 0x7fffu + ((u >> 16) & 1u)) >> 16;
  return (short)r;
}

__device__ __forceinline__ short8 pack8(float4 a, float4 b) {
  short8 v;
  v[0] = f2bf(a.x); v[1] = f2bf(a.y); v[2] = f2bf(a.z); v[3] = f2bf(a.w);
  v[4] = f2bf(b.x); v[5] = f2bf(b.y); v[6] = f2bf(b.z); v[7] = f2bf(b.w);
  return v;
}

// Swizzled LDS tile [rows][64] bf16. Granule = 8 elems (16B).
// Slot gs of row r holds global granule gs ^ (r&7).
__device__ __forceinline__ int swz(int r, int gran) {
  return r * 64 + ((gran ^ (r & 7)) << 3);
}

// ---------------- RoPE cos/sin table ----------------
__global__ void rope_table_kernel(const int* __restrict__ tp,
                                  float* __restrict__ ct, float* __restrict__ st) {
  int idx = blockIdx.x * 256 + threadIdx.x;
  if (idx >= SEQ * 32) return;
  int s = idx >> 5, i = idx & 31;
  int is64 = (tp[1] == 0);
  int p = is64 ? tp[2 * s] : tp[s];
  float invf = powf(10000.0f, -(2.0f * (float)i) / 64.0f);
  float a = (float)p * invf;
  ct[idx] = cosf(a);
  st[idx] = sinf(a);
}

// ---------------- precast fp32 -> bf16 (X, Wq, Wk, Wv, Wo) ----------------
__global__ __launch_bounds__(256) void precast_kernel(
    const float* __restrict__ X, const float* __restrict__ Wq,
    const float* __restrict__ Wk, const float* __restrict__ Wv,
    const float* __restrict__ Wo,
    short* __restrict__ Xb, short* __restrict__ Wqb, short* __restrict__ Wkb,
    short* __restrict__ Wvb, short* __restrict__ Wob) {
  int i = blockIdx.x * 256 + threadIdx.x;
  const float* src; short* dst; int off;
  if (i < 524288) { src = X; dst = Xb; off = i; }
  else {
    int k = i - 524288; int w = k >> 17; off = k & 131071;
    src = (w == 0) ? Wq : (w == 1) ? Wk : (w == 2) ? Wv : Wo;
    dst = (w == 0) ? Wqb : (w == 1) ? Wkb : (w == 2) ? Wvb : Wob;
  }
  const float4* p = reinterpret_cast<const float4*>(src) + 2 * (size_t)off;
  float4 a = p[0], b = p[1];
  reinterpret_cast<short8*>(dst)[off] = pack8(a, b);
}

// ---------------- fused QKV projection + RoPE, 128x128 tile + GLDS ----------
__global__ __launch_bounds__(256) void gemm_qkv_kernel(
    const short* __restrict__ X, const short* __restrict__ Wq,
    const short* __restrict__ Wk, const short* __restrict__ Wv,
    short* __restrict__ Qb, short* __restrict__ Kb, short* __restrict__ Vb,
    const float* __restrict__ ct, const float* __restrict__ st) {
  __shared__ __align__(16) short As[128 * 64];
  __shared__ __align__(16) short Bs[128 * 64];
  const int tm = blockIdx.x;          // 32 (M tiles of 128)
  const int tn = blockIdx.y;          // 24 (N tiles of 128 across 3 matrices)
  const int tid = threadIdx.x;
  const int wave = tid >> 6, lane = tid & 63;
  const int l15 = lane & 15, quad = lane >> 4;
  const int wm = wave >> 1, wn = wave & 1;   // 2x2 wave grid, 64x64 each

  const int mid = tn >> 3;             // 0=Q 1=K 2=V
  const int n0 = (tn & 7) * 128;
  const short* W = (mid == 0) ? Wq : (mid == 1 ? Wk : Wv);
  const short* Abase = X + (size_t)(tm * 128) * DMODEL;
  const short* Bbase = W + (size_t)n0 * DMODEL;

  const int lr = lane >> 3;            // row within 8-row chunk
  const int lc = (lane & 7) ^ lr;      // XOR-permuted source granule

  f32x4 acc[4][4];
#pragma unroll
  for (int mb = 0; mb < 4; mb++)
#pragma unroll
    for (int nb = 0; nb < 4; nb++) acc[mb][nb] = (f32x4){0.f, 0.f, 0.f, 0.f};

  for (int kk = 0; kk < 16; kk++) {
    const short* Ak = Abase + kk * 64;
    const short* Bk = Bbase + kk * 64;
#pragma unroll
    for (int i = 0; i < 4; i++) {
      int R = i * 32 + wave * 8;
      GLDS16(Ak + (size_t)(R + lr) * DMODEL + lc * 8, &As[R * 64 + lane * 8]);
    }
#pragma unroll
    for (int i = 0; i < 4; i++) {
      int R = i * 32 + wave * 8;
      GLDS16(Bk + (size_t)(R + lr) * DMODEL + lc * 8, &Bs[R * 64 + lane * 8]);
    }
    __syncthreads();   // drains vmcnt(0): GLDS complete
#pragma unroll
    for (int kg = 0; kg < 2; kg++) {
      short8 af[4], bf[4];
#pragma unroll
      for (int mb = 0; mb < 4; mb++) {
        int r = wm * 64 + mb * 16 + l15;
        af[mb] = *reinterpret_cast<const short8*>(&As[swz(r, kg * 4 + quad)]);
      }
#pragma unroll
      for (int nb = 0; nb < 4; nb++) {
        int r = wn * 64 + nb * 16 + l15;
        bf[nb] = *reinterpret_cast<const short8*>(&Bs[swz(r, kg * 4 + quad)]);
      }
#pragma unroll
      for (int mb = 0; mb < 4; mb++)
#pragma unroll
        for (int nb = 0; nb < 4; nb++)
          acc[mb][nb] = __builtin_amdgcn_mfma_f32_16x16x32_bf16(af[mb], bf[nb], acc[mb][nb], 0, 0, 0);
    }
    __syncthreads();
  }

  // epilogue: scatter into (B,H,S,64); RoPE for Q,K via lane-pair shuffle
#pragma unroll
  for (int mb = 0; mb < 4; mb++)
#pragma unroll
    for (int nb = 0; nb < 4; nb++) {
      int nl = n0 + wn * 64 + nb * 16 + l15;
      int h = nl >> 6, dd = nl & 63;
#pragma unroll
      for (int reg = 0; reg < 4; reg++) {
        int rg = tm * 128 + wm * 64 + mb * 16 + quad * 4 + reg;
        int b = rg >> 11, s = rg & 2047;
        float v = acc[mb][nb][reg];
        size_t oi = (((size_t)(b * NHEADS + h)) * SEQ + s) * DKH + dd;
        if (mid == 2) {
          Vb[oi] = f2bf(v);
        } else {
          float pv = __shfl_xor(v, 1);
          int fi = dd >> 1;
          float c = ct[s * 32 + fi], sn = st[s * 32 + fi];
          float o = (dd & 1) ? (pv * sn + v * c) : (v * c - pv * sn);
          ((mid == 0) ? Qb : Kb)[oi] = f2bf(o);
        }
      }
    }
}

// ---------------- flash attention (causal), round-6 winner (unchanged) ------
__global__ __launch_bounds__(256, 4) void attn_kernel(
    const short* __restrict__ Qb, const short* __restrict__ Kb,
    const short* __restrict__ Vb, short* __restrict__ Ob) {
  __shared__ __align__(16) short QPs[64 * 64];     // Q staging, then P tiles
  __shared__ __align__(16) short Ks[2][64 * 64];
  __shared__ __align__(16) short Vs[2][64 * 64];   // transposed: [dv][key]

  const int id = blockIdx.x;
  const int xx = id & 7;
  const int mm = (((id >> 3) & 3) + (id >> 8)) & 3;
  const int bh = id >> 5;
  const int qt = (mm == 0) ? (31 - xx) : (mm == 1) ? (16 + xx)
               : (mm == 2) ? (15 - xx) : xx;

  const int tid = threadIdx.x;
  const int wave = tid >> 6, lane = tid & 63;
  const int l15 = lane & 15, quad = lane >> 4;
  const int sr0 = tid >> 3, sc = tid & 7;

  const short* Qp = Qb + (size_t)bh * SEQ * DKH;
  const short* Kp = Kb + (size_t)bh * SEQ * DKH;
  const short* Vp = Vb + (size_t)bh * SEQ * DKH;

  uint4 kreg[2], vreg[2];
#pragma unroll
  for (int i = 0; i < 2; i++) {
    int r = sr0 + i * 32;
    kreg[i] = *reinterpret_cast<const uint4*>(Kp + (size_t)r * DKH + sc * 8);
    vreg[i] = *reinterpret_cast<const uint4*>(Vp + (size_t)r * DKH + sc * 8);
  }
#pragma unroll
  for (int i = 0; i < 2; i++) {
    int r = sr0 + i * 32;
    uint4 v = *reinterpret_cast<const uint4*>(Qp + (size_t)(qt * 64 + r) * DKH + sc * 8);
    *reinterpret_cast<uint4*>(&QPs[swz(r, sc)]) = v;
  }
#pragma unroll
  for (int i = 0; i < 2; i++) {
    int r = sr0 + i * 32;
    *reinterpret_cast<uint4*>(&Ks[0][swz(r, sc)]) = kreg[i];
    const short* vsp = reinterpret_cast<const short*>(&vreg[i]);
#pragma unroll
    for (int j = 0; j < 8; j++) {
      int dv = sc * 8 + j;
      Vs[0][dv * 64 + ((((r >> 3) ^ (dv & 7) ^ (dv >> 3)) & 7) << 3) + (r & 7)] = vsp[j];
    }
  }
  __syncthreads();
  short8 qf0, qf1;
  {
    int r = wave * 16 + l15;
    qf0 = *reinterpret_cast<const short8*>(&QPs[swz(r, quad)]);
    qf1 = *reinterpret_cast<const short8*>(&QPs[swz(r, 4 + quad)]);
  }

  f32x4 accO[4];
#pragma unroll
  for (int i = 0; i < 4; i++) accO[i] = (f32x4){0.f, 0.f, 0.f, 0.f};
  float rs[4] = {0.f, 0.f, 0.f, 0.f};

  const float SCL = 0.125f * 1.44269504089f;   // 1/sqrt(64) * log2(e)
  const float FM = 13.0f;                      // fixed softmax shift (exact)

  int buf = 0;
  for (int kt = 0; kt <= qt; kt++) {
    if (kt < qt) {
#pragma unroll
      for (int i = 0; i < 2; i++) {
        int r = (kt + 1) * 64 + sr0 + i * 32;
        kreg[i] = *reinterpret_cast<const uint4*>(Kp + (size_t)r * DKH + sc * 8);
        vreg[i] = *reinterpret_cast<const uint4*>(Vp + (size_t)r * DKH + sc * 8);
      }
    }

    f32x4 sa[4];
#pragma unroll
    for (int nb = 0; nb < 4; nb++) {
      sa[nb] = (f32x4){0.f, 0.f, 0.f, 0.f};
      int r = nb * 16 + l15;
      short8 kf0 = *reinterpret_cast<const short8*>(&Ks[buf][swz(r, quad)]);
      sa[nb] = __builtin_amdgcn_mfma_f32_16x16x32_bf16(qf0, kf0, sa[nb], 0, 0, 0);
      short8 kf1 = *reinterpret_cast<const short8*>(&Ks[buf][swz(r, 4 + quad)]);
      sa[nb] = __builtin_amdgcn_mfma_f32_16x16x32_bf16(qf1, kf1, sa[nb], 0, 0, 0);
    }

    const bool diag = (kt == qt);
#pragma unroll
    for (int nb = 0; nb < 4; nb++)
#pragma unroll
      for (int reg = 0; reg < 4; reg++) {
        float p = exp2f(sa[nb][reg] * SCL - FM);
        if (diag && (nb * 16 + l15) > (wave * 16 + quad * 4 + reg)) p = 0.f;
        rs[reg] += p;
        int r = quad * 4 + reg, col = nb * 16 + l15;
        QPs[swz(wave * 16 + r, col >> 3) + (col & 7)] = f2bf(p);
      }

    short8 pf0, pf1;
    {
      int r = wave * 16 + l15;
      pf0 = *reinterpret_cast<const short8*>(&QPs[swz(r, quad)]);
      pf1 = *reinterpret_cast<const short8*>(&QPs[swz(r, 4 + quad)]);
    }
#pragma unroll
    for (int db = 0; db < 4; db++) {
      int dv = db * 16 + l15;
      int fsw = (dv & 7) ^ (dv >> 3);
      short8 vf0 = *reinterpret_cast<const short8*>(
          &Vs[buf][dv * 64 + (((quad ^ fsw) & 7) << 3)]);
      accO[db] = __builtin_amdgcn_mfma_f32_16x16x32_bf16(pf0, vf0, accO[db], 0, 0, 0);
      short8 vf1 = *reinterpret_cast<const short8*>(
          &Vs[buf][dv * 64 + ((((quad + 4) ^ fsw) & 7) << 3)]);
      accO[db] = __builtin_amdgcn_mfma_f32_16x16x32_bf16(pf1, vf1, accO[db], 0, 0, 0);
    }

    if (kt < qt) {
      int nbuf = buf ^ 1;
#pragma unroll
      for (int i = 0; i < 2; i++) {
        int r = sr0 + i * 32;
        *reinterpret_cast<uint4*>(&Ks[nbuf][swz(r, sc)]) = kreg[i];
        const short* vsp = reinterpret_cast<const short*>(&vreg[i]);
#pragma unroll
        for (int j = 0; j < 8; j++) {
          int dv = sc * 8 + j;
          Vs[nbuf][dv * 64 + ((((r >> 3) ^ (dv & 7) ^ (dv >> 3)) & 7) << 3) + (r & 7)] = vsp[j];
        }
      }
      __syncthreads();
      buf = nbuf;
    }
  }

  float lrow[4];
#pragma unroll
  for (int reg = 0; reg < 4; reg++) {
    float t = rs[reg];
#pragma unroll
    for (int off = 1; off < 16; off <<= 1) t += __shfl_xor(t, off);
    lrow[reg] = t;
  }

  int b = bh >> 4, h = bh & 15;
#pragma unroll
  for (int db = 0; db < 4; db++)
#pragma unroll
    for (int reg = 0; reg < 4; reg++) {
      int s = qt * 64 + wave * 16 + quad * 4 + reg;
      int dv = db * 16 + l15;
      float o = accO[db][reg] / lrow[reg];
      Ob[((size_t)(b * SEQ + s)) * DMODEL + h * DKH + dv] = f2bf(o);
    }
}

// ---------------- output projection, 128x64 tile + GLDS (fp32 output) -------
__global__ __launch_bounds__(256) void gemm_out_kernel(
    const short* __restrict__ X, const short* __restrict__ Wo, float* __restrict__ Out) {
  __shared__ __align__(16) short As[128 * 64];
  __shared__ __align__(16) short Bs[64 * 64];
  const int tm = blockIdx.x;   // 32 (M tiles of 128)
  const int tn = blockIdx.y;   // 16 (N tiles of 64)
  const int tid = threadIdx.x;
  const int wave = tid >> 6, lane = tid & 63;
  const int l15 = lane & 15, quad = lane >> 4;
  const int wm = wave >> 1, wn = wave & 1;   // wave tile 64M x 32N

  const short* Abase = X + (size_t)(tm * 128) * DMODEL;
  const short* Bbase = Wo + (size_t)(tn * 64) * DMODEL;

  const int lr = lane >> 3;
  const int lc = (lane & 7) ^ lr;

  f32x4 acc[4][2];
#pragma unroll
  for (int mb = 0; mb < 4; mb++)
#pragma unroll
    for (int nb = 0; nb < 2; nb++) acc[mb][nb] = (f32x4){0.f, 0.f, 0.f, 0.f};

  for (int kk = 0; kk < 16; kk++) {
    const short* Ak = Abase + kk * 64;
    const short* Bk = Bbase + kk * 64;
#pragma unroll
    for (int i = 0; i < 4; i++) {
      int R = i * 32 + wave * 8;
      GLDS16(Ak + (size_t)(R + lr) * DMODEL + lc * 8, &As[R * 64 + lane * 8]);
    }
#pragma unroll
    for (int i = 0; i < 2; i++) {
      int R = i * 32 + wave * 8;
      GLDS16(Bk + (size_t)(R + lr) * DMODEL + lc * 8, &Bs[R * 64 + lane * 8]);
    }
    __syncthreads();
#pragma unroll
    for (int kg = 0; kg < 2; kg++) {
      short8 af[4], bf[2];
#pragma unroll
      for (int mb = 0; mb < 4; mb++) {
        int r = wm * 64 + mb * 16 + l15;
        af[mb] = *reinterpret_cast<const short8*>(&As[swz(r, kg * 4 + quad)]);
      }
#pragma unroll
      for (int nb = 0; nb < 2; nb++) {
        int r = wn * 32 + nb * 16 + l15;
        bf[nb] = *reinterpret_cast<const short8*>(&Bs[swz(r, kg * 4 + quad)]);
      }
#pragma unroll
      for (int mb = 0; mb < 4; mb++)
#pragma unroll
        for (int nb = 0; nb < 2; nb++)
          acc[mb][nb] = __builtin_amdgcn_mfma_f32_16x16x32_bf16(af[mb], bf[nb], acc[mb][nb], 0, 0, 0);
    }
    __syncthreads();
  }
#pragma unroll
  for (int mb = 0; mb < 4; mb++)
#pragma unroll
    for (int nb = 0; nb < 2; nb++)
#pragma unroll
      for (int reg = 0; reg < 4; reg++) {
        int rg = tm * 128 + wm * 64 + mb * 16 + quad * 4 + reg;
        int col = tn * 64 + wn * 32 + nb * 16 + l15;
        Out[(size_t)rg * DMODEL + col] = acc[mb][nb][reg];
      }
}

extern "C" void kernel_launch(void* const* d_in, const int* in_sizes, int n_in,
                              void* d_out, int out_size, void* d_ws, size_t ws_size,
                              hipStream_t stream) {
  (void)in_sizes; (void)n_in; (void)out_size; (void)ws_size;
  const float* X  = (const float*)d_in[0];
  const int*   tp = (const int*)d_in[1];
  const float* Wq = (const float*)d_in[2];
  const float* Wk = (const float*)d_in[3];
  const float* Wv = (const float*)d_in[4];
  const float* Wo = (const float*)d_in[5];
  float* Out = (float*)d_out;

  short* Qb  = (short*)d_ws;           // 4M shorts each
  short* Kb  = Qb + 4194304;
  short* Vb  = Kb + 4194304;
  short* Ab  = Vb + 4194304;
  short* Xb  = Ab + 4194304;           // 4M
  short* Wqb = Xb + 4194304;           // 1M each
  short* Wkb = Wqb + 1048576;
  short* Wvb = Wkb + 1048576;
  short* Wob = Wvb + 1048576;
  float* ct  = (float*)(Wob + 1048576);
  float* st  = ct + SEQ * 32;

  rope_table_kernel<<<dim3(256), dim3(256), 0, stream>>>(tp, ct, st);
  precast_kernel<<<dim3(4096), dim3(256), 0, stream>>>(X, Wq, Wk, Wv, Wo,
                                                       Xb, Wqb, Wkb, Wvb, Wob);
  gemm_qkv_kernel<<<dim3(32, 24), dim3(256), 0, stream>>>(Xb, Wqb, Wkb, Wvb,
                                                          Qb, Kb, Vb, ct, st);
  attn_kernel<<<dim3(1024), dim3(256), 0, stream>>>(Qb, Kb, Vb, Ab);
  gemm_out_kernel<<<dim3(32, 16), dim3(256), 0, stream>>>(Ab, Wob, Out);
}

// Round 8
// 187.932 us; speedup vs baseline: 1.1596x; 1.1596x over previous
//
#include <hip/hip_runtime.h>
#include <hip/hip_bf16.h>
#include <math.h>

#define NHEADS 16
#define DKH 64
#define SEQ 2048
#define DMODEL 1024

typedef __attribute__((ext_vector_type(8))) short short8;
typedef __attribute__((ext_vector_type(4))) float f32x4;

// async global->LDS, 16B per lane. LDS dest = wave-uniform base + lane*16.
#define GLDS16(g, l)                                         \
  __builtin_amdgcn_global_load_lds(                          \
      (__attribute__((address_space(1))) void*)(void*)(g),   \
      (__attribute__((address_space(3))) void*)(l), 16, 0, 0)

__device__ __forceinline__ short f2bf(float f) {
  unsigned u = __float_as_uint(f);
  unsigned r = (u + 0x7fffu + ((u >> 16) & 1u)) >> 16;
  return (short)r;
}

__device__ __forceinline__ short8 pack8(float4 a, float4 b) {
  short8 v;
  v[0] = f2bf(a.x); v[1] = f2bf(a.y); v[2] = f2bf(a.z); v[3] = f2bf(a.w);
  v[4] = f2bf(b.x); v[5] = f2bf(b.y); v[6] = f2bf(b.z); v[7] = f2bf(b.w);
  return v;
}

// Swizzled LDS tile [rows][64] bf16. Granule = 8 elems (16B).
// Slot gs of row r holds global granule gs ^ (r&7).
__device__ __forceinline__ int swz(int r, int gran) {
  return r * 64 + ((gran ^ (r & 7)) << 3);
}

// ---------------- precast fp32 -> bf16 + RoPE table (merged) ----------------
__global__ __launch_bounds__(256) void precast_rope_kernel(
    const float* __restrict__ X, const float* __restrict__ Wq,
    const float* __restrict__ Wk, const float* __restrict__ Wv,
    const float* __restrict__ Wo, const int* __restrict__ tp,
    short* __restrict__ Xb, short* __restrict__ Wqb, short* __restrict__ Wkb,
    short* __restrict__ Wvb, short* __restrict__ Wob,
    float* __restrict__ ct, float* __restrict__ st) {
  int bid = blockIdx.x;
  if (bid < 4096) {
    int i = bid * 256 + threadIdx.x;
    const float* src; short* dst; int off;
    if (i < 524288) { src = X; dst = Xb; off = i; }
    else {
      int k = i - 524288; int w = k >> 17; off = k & 131071;
      src = (w == 0) ? Wq : (w == 1) ? Wk : (w == 2) ? Wv : Wo;
      dst = (w == 0) ? Wqb : (w == 1) ? Wkb : (w == 2) ? Wvb : Wob;
    }
    const float4* p = reinterpret_cast<const float4*>(src) + 2 * (size_t)off;
    float4 a = p[0], b = p[1];
    reinterpret_cast<short8*>(dst)[off] = pack8(a, b);
  } else {
    int idx = (bid - 4096) * 256 + threadIdx.x;
    if (idx >= SEQ * 32) return;
    int s = idx >> 5, i = idx & 31;
    int is64 = (tp[1] == 0);
    int p = is64 ? tp[2 * s] : tp[s];
    float invf = powf(10000.0f, -(2.0f * (float)i) / 64.0f);
    float a = (float)p * invf;
    ct[idx] = cosf(a);
    st[idx] = sinf(a);
  }
}

// ---------------- fused QKV projection + RoPE, 128x128 tile + GLDS ----------
// Q,K stored (B,H,S,64) with RoPE applied; V stored TRANSPOSED (B,H,64,S).
__global__ __launch_bounds__(256) void gemm_qkv_kernel(
    const short* __restrict__ X, const short* __restrict__ Wq,
    const short* __restrict__ Wk, const short* __restrict__ Wv,
    short* __restrict__ Qb, short* __restrict__ Kb, short* __restrict__ Vb,
    const float* __restrict__ ct, const float* __restrict__ st) {
  __shared__ __align__(16) short As[128 * 64];
  __shared__ __align__(16) short Bs[128 * 64];
  const int tm = blockIdx.x;          // 32 (M tiles of 128)
  const int tn = blockIdx.y;          // 24 (N tiles of 128 across 3 matrices)
  const int tid = threadIdx.x;
  const int wave = tid >> 6, lane = tid & 63;
  const int l15 = lane & 15, quad = lane >> 4;
  const int wm = wave >> 1, wn = wave & 1;   // 2x2 wave grid, 64x64 each

  const int mid = tn >> 3;             // 0=Q 1=K 2=V
  const int n0 = (tn & 7) * 128;
  const short* W = (mid == 0) ? Wq : (mid == 1 ? Wk : Wv);
  const short* Abase = X + (size_t)(tm * 128) * DMODEL;
  const short* Bbase = W + (size_t)n0 * DMODEL;

  const int lr = lane >> 3;            // row within 8-row chunk
  const int lc = (lane & 7) ^ lr;      // XOR-permuted source granule

  f32x4 acc[4][4];
#pragma unroll
  for (int mb = 0; mb < 4; mb++)
#pragma unroll
    for (int nb = 0; nb < 4; nb++) acc[mb][nb] = (f32x4){0.f, 0.f, 0.f, 0.f};

  for (int kk = 0; kk < 16; kk++) {
    const short* Ak = Abase + kk * 64;
    const short* Bk = Bbase + kk * 64;
#pragma unroll
    for (int i = 0; i < 4; i++) {
      int R = i * 32 + wave * 8;
      GLDS16(Ak + (size_t)(R + lr) * DMODEL + lc * 8, &As[R * 64 + lane * 8]);
    }
#pragma unroll
    for (int i = 0; i < 4; i++) {
      int R = i * 32 + wave * 8;
      GLDS16(Bk + (size_t)(R + lr) * DMODEL + lc * 8, &Bs[R * 64 + lane * 8]);
    }
    __syncthreads();   // drains vmcnt(0): GLDS complete
#pragma unroll
    for (int kg = 0; kg < 2; kg++) {
      short8 af[4], bf[4];
#pragma unroll
      for (int mb = 0; mb < 4; mb++) {
        int r = wm * 64 + mb * 16 + l15;
        af[mb] = *reinterpret_cast<const short8*>(&As[swz(r, kg * 4 + quad)]);
      }
#pragma unroll
      for (int nb = 0; nb < 4; nb++) {
        int r = wn * 64 + nb * 16 + l15;
        bf[nb] = *reinterpret_cast<const short8*>(&Bs[swz(r, kg * 4 + quad)]);
      }
#pragma unroll
      for (int mb = 0; mb < 4; mb++)
#pragma unroll
        for (int nb = 0; nb < 4; nb++)
          acc[mb][nb] = __builtin_amdgcn_mfma_f32_16x16x32_bf16(af[mb], bf[nb], acc[mb][nb], 0, 0, 0);
    }
    __syncthreads();
  }

  // epilogue
#pragma unroll
  for (int mb = 0; mb < 4; mb++) {
    const int s0g = tm * 128 + wm * 64 + mb * 16 + quad * 4;   // rows s0g..s0g+3
    const int b = s0g >> 11, s = s0g & 2047;
#pragma unroll
    for (int nb = 0; nb < 4; nb++) {
      int nl = n0 + wn * 64 + nb * 16 + l15;
      int h = nl >> 6, dd = nl & 63;
      if (mid == 2) {
        // V: packed b64 transposed store -> Vb[(b,h)][dd][s..s+3]
        unsigned u0 = (unsigned)(unsigned short)f2bf(acc[mb][nb][0]) |
                      ((unsigned)(unsigned short)f2bf(acc[mb][nb][1]) << 16);
        unsigned u1 = (unsigned)(unsigned short)f2bf(acc[mb][nb][2]) |
                      ((unsigned)(unsigned short)f2bf(acc[mb][nb][3]) << 16);
        uint2 pk; pk.x = u0; pk.y = u1;
        *reinterpret_cast<uint2*>(Vb + ((size_t)(b * NHEADS + h) * DKH + dd) * SEQ + s) = pk;
      } else {
#pragma unroll
        for (int reg = 0; reg < 4; reg++) {
          float v = acc[mb][nb][reg];
          float pv = __shfl_xor(v, 1);
          int fi = dd >> 1;
          int sg = s + reg;
          float c = ct[sg * 32 + fi], sn = st[sg * 32 + fi];
          float o = (dd & 1) ? (pv * sn + v * c) : (v * c - pv * sn);
          size_t oi = (((size_t)(b * NHEADS + h)) * SEQ + sg) * DKH + dd;
          ((mid == 0) ? Qb : Kb)[oi] = f2bf(o);
        }
      }
    }
  }
}

// ---------------- flash attention (causal), round 8: S^T scheme -------------
// S^T = K·Q^T (operand swap): lane's 4 C-regs = 4 consecutive keys of ONE
// q-row -> P written as packed b64 (4/iter vs 16 b16); rs is scalar/lane.
// V pre-transposed (B,H,D,S) -> staged like K (2 uint4), no scatter.
// Fixed-max base-2 softmax (exact). LDS 40KB -> 4 blocks/CU.
__global__ __launch_bounds__(256, 4) void attn_kernel(
    const short* __restrict__ Qb, const short* __restrict__ Kb,
    const short* __restrict__ Vtb, short* __restrict__ Ob) {
  __shared__ __align__(16) short QPs[64 * 64];     // Q staging, then P tiles
  __shared__ __align__(16) short Ks[2][64 * 64];   // [key][d]
  __shared__ __align__(16) short Vs[2][64 * 64];   // [dv][key] (from Vtb rows)

  const int id = blockIdx.x;
  const int xx = id & 7;
  const int mm = (((id >> 3) & 3) + (id >> 8)) & 3;
  const int bh = id >> 5;
  const int qt = (mm == 0) ? (31 - xx) : (mm == 1) ? (16 + xx)
               : (mm == 2) ? (15 - xx) : xx;

  const int tid = threadIdx.x;
  const int wave = tid >> 6, lane = tid & 63;
  const int l15 = lane & 15, quad = lane >> 4;
  const int sr0 = tid >> 3, sc = tid & 7;

  const short* Qp = Qb + (size_t)bh * SEQ * DKH;
  const short* Kp = Kb + (size_t)bh * SEQ * DKH;
  const short* Vp = Vtb + (size_t)bh * DKH * SEQ;  // rows = dv, cols = s

  uint4 kreg[2], vreg[2];
#pragma unroll
  for (int i = 0; i < 2; i++) {
    int r = sr0 + i * 32;
    kreg[i] = *reinterpret_cast<const uint4*>(Kp + (size_t)r * DKH + sc * 8);
    vreg[i] = *reinterpret_cast<const uint4*>(Vp + (size_t)r * SEQ + sc * 8);
  }
#pragma unroll
  for (int i = 0; i < 2; i++) {
    int r = sr0 + i * 32;
    uint4 v = *reinterpret_cast<const uint4*>(Qp + (size_t)(qt * 64 + r) * DKH + sc * 8);
    *reinterpret_cast<uint4*>(&QPs[swz(r, sc)]) = v;
  }
#pragma unroll
  for (int i = 0; i < 2; i++) {
    int r = sr0 + i * 32;
    *reinterpret_cast<uint4*>(&Ks[0][swz(r, sc)]) = kreg[i];
    *reinterpret_cast<uint4*>(&Vs[0][swz(r, sc)]) = vreg[i];
  }
  __syncthreads();
  short8 qf0, qf1;
  {
    int r = wave * 16 + l15;
    qf0 = *reinterpret_cast<const short8*>(&QPs[swz(r, quad)]);
    qf1 = *reinterpret_cast<const short8*>(&QPs[swz(r, 4 + quad)]);
  }

  f32x4 accO[4];
#pragma unroll
  for (int i = 0; i < 4; i++) accO[i] = (f32x4){0.f, 0.f, 0.f, 0.f};
  float rs = 0.f;   // partial row-sum for q-row (wave*16+l15), this lane's keys

  const float SCL = 0.125f * 1.44269504089f;   // 1/sqrt(64) * log2(e)
  const float FM = 13.0f;                      // fixed softmax shift (exact)

  int buf = 0;
  for (int kt = 0; kt <= qt; kt++) {
    if (kt < qt) {
#pragma unroll
      for (int i = 0; i < 2; i++) {
        int r = sr0 + i * 32;
        kreg[i] = *reinterpret_cast<const uint4*>(Kp + (size_t)((kt + 1) * 64 + r) * DKH + sc * 8);
        vreg[i] = *reinterpret_cast<const uint4*>(Vp + (size_t)r * SEQ + (kt + 1) * 64 + sc * 8);
      }
    }

    // S^T = K Q^T : D[m=key][n=qrow]; lane holds keys nb*16+quad*4+{0..3},
    // q-row = wave*16+l15.
    f32x4 sa[4];
#pragma unroll
    for (int nb = 0; nb < 4; nb++) {
      sa[nb] = (f32x4){0.f, 0.f, 0.f, 0.f};
      int r = nb * 16 + l15;
      short8 kf0 = *reinterpret_cast<const short8*>(&Ks[buf][swz(r, quad)]);
      sa[nb] = __builtin_amdgcn_mfma_f32_16x16x32_bf16(kf0, qf0, sa[nb], 0, 0, 0);
      short8 kf1 = *reinterpret_cast<const short8*>(&Ks[buf][swz(r, 4 + quad)]);
      sa[nb] = __builtin_amdgcn_mfma_f32_16x16x32_bf16(kf1, qf1, sa[nb], 0, 0, 0);
    }

    const bool diag = (kt == qt);
    const int prow = wave * 16 + l15;          // this lane's q-row (P row)
#pragma unroll
    for (int nb = 0; nb < 4; nb++) {
      float p0 = exp2f(sa[nb][0] * SCL - FM);
      float p1 = exp2f(sa[nb][1] * SCL - FM);
      float p2 = exp2f(sa[nb][2] * SCL - FM);
      float p3 = exp2f(sa[nb][3] * SCL - FM);
      if (diag) {
        int kbase = nb * 16 + quad * 4;
        if (kbase + 0 > prow) p0 = 0.f;
        if (kbase + 1 > prow) p1 = 0.f;
        if (kbase + 2 > prow) p2 = 0.f;
        if (kbase + 3 > prow) p3 = 0.f;
      }
      rs += (p0 + p1) + (p2 + p3);
      unsigned u0 = (unsigned)(unsigned short)f2bf(p0) |
                    ((unsigned)(unsigned short)f2bf(p1) << 16);
      unsigned u1 = (unsigned)(unsigned short)f2bf(p2) |
                    ((unsigned)(unsigned short)f2bf(p3) << 16);
      uint2 pk; pk.x = u0; pk.y = u1;
      int g = 2 * nb + (quad >> 1);            // granule of keys 16nb+8*(q>>1)
      *reinterpret_cast<uint2*>(&QPs[swz(prow, g) + (quad & 1) * 4]) = pk;
    }

    // O += P V : A = P (row=qrow=l15, keys u*32+quad*8+..), B = V^T rows
    short8 pf0 = *reinterpret_cast<const short8*>(&QPs[swz(prow, quad)]);
    short8 pf1 = *reinterpret_cast<const short8*>(&QPs[swz(prow, 4 + quad)]);
#pragma unroll
    for (int db = 0; db < 4; db++) {
      int dv = db * 16 + l15;
      short8 vf0 = *reinterpret_cast<const short8*>(&Vs[buf][swz(dv, quad)]);
      accO[db] = __builtin_amdgcn_mfma_f32_16x16x32_bf16(pf0, vf0, accO[db], 0, 0, 0);
      short8 vf1 = *reinterpret_cast<const short8*>(&Vs[buf][swz(dv, 4 + quad)]);
      accO[db] = __builtin_amdgcn_mfma_f32_16x16x32_bf16(pf1, vf1, accO[db], 0, 0, 0);
    }

    if (kt < qt) {
      int nbuf = buf ^ 1;
#pragma unroll
      for (int i = 0; i < 2; i++) {
        int r = sr0 + i * 32;
        *reinterpret_cast<uint4*>(&Ks[nbuf][swz(r, sc)]) = kreg[i];
        *reinterpret_cast<uint4*>(&Vs[nbuf][swz(r, sc)]) = vreg[i];
      }
      __syncthreads();
      buf = nbuf;
    }
  }

  // reduce rs across the 4 quads sharing each l15 (full row sum)
  float t = rs;
  t += __shfl_xor(t, 16);
  t += __shfl_xor(t, 32);
  // accO rows are qrow = quad*4+reg; fetch lrow from lane l15 = quad*4+reg
  float lv[4];
#pragma unroll
  for (int reg = 0; reg < 4; reg++) lv[reg] = __shfl(t, quad * 4 + reg);

  // write (B,S,1024) bf16
  int b = bh >> 4, h = bh & 15;
#pragma unroll
  for (int db = 0; db < 4; db++)
#pragma unroll
    for (int reg = 0; reg < 4; reg++) {
      int s = qt * 64 + wave * 16 + quad * 4 + reg;
      int dv = db * 16 + l15;
      float o = accO[db][reg] / lv[reg];
      Ob[((size_t)(b * SEQ + s)) * DMODEL + h * DKH + dv] = f2bf(o);
    }
}

// ---------------- output projection, 128x64 tile + GLDS (fp32 output) -------
__global__ __launch_bounds__(256) void gemm_out_kernel(
    const short* __restrict__ X, const short* __restrict__ Wo, float* __restrict__ Out) {
  __shared__ __align__(16) short As[128 * 64];
  __shared__ __align__(16) short Bs[64 * 64];
  const int tm = blockIdx.x;   // 32 (M tiles of 128)
  const int tn = blockIdx.y;   // 16 (N tiles of 64)
  const int tid = threadIdx.x;
  const int wave = tid >> 6, lane = tid & 63;
  const int l15 = lane & 15, quad = lane >> 4;
  const int wm = wave >> 1, wn = wave & 1;   // wave tile 64M x 32N

  const short* Abase = X + (size_t)(tm * 128) * DMODEL;
  const short* Bbase = Wo + (size_t)(tn * 64) * DMODEL;

  const int lr = lane >> 3;
  const int lc = (lane & 7) ^ lr;

  f32x4 acc[4][2];
#pragma unroll
  for (int mb = 0; mb < 4; mb++)
#pragma unroll
    for (int nb = 0; nb < 2; nb++) acc[mb][nb] = (f32x4){0.f, 0.f, 0.f, 0.f};

  for (int kk = 0; kk < 16; kk++) {
    const short* Ak = Abase + kk * 64;
    const short* Bk = Bbase + kk * 64;
#pragma unroll
    for (int i = 0; i < 4; i++) {
      int R = i * 32 + wave * 8;
      GLDS16(Ak + (size_t)(R + lr) * DMODEL + lc * 8, &As[R * 64 + lane * 8]);
    }
#pragma unroll
    for (int i = 0; i < 2; i++) {
      int R = i * 32 + wave * 8;
      GLDS16(Bk + (size_t)(R + lr) * DMODEL + lc * 8, &Bs[R * 64 + lane * 8]);
    }
    __syncthreads();
#pragma unroll
    for (int kg = 0; kg < 2; kg++) {
      short8 af[4], bf[2];
#pragma unroll
      for (int mb = 0; mb < 4; mb++) {
        int r = wm * 64 + mb * 16 + l15;
        af[mb] = *reinterpret_cast<const short8*>(&As[swz(r, kg * 4 + quad)]);
      }
#pragma unroll
      for (int nb = 0; nb < 2; nb++) {
        int r = wn * 32 + nb * 16 + l15;
        bf[nb] = *reinterpret_cast<const short8*>(&Bs[swz(r, kg * 4 + quad)]);
      }
#pragma unroll
      for (int mb = 0; mb < 4; mb++)
#pragma unroll
        for (int nb = 0; nb < 2; nb++)
          acc[mb][nb] = __builtin_amdgcn_mfma_f32_16x16x32_bf16(af[mb], bf[nb], acc[mb][nb], 0, 0, 0);
    }
    __syncthreads();
  }
#pragma unroll
  for (int mb = 0; mb < 4; mb++)
#pragma unroll
    for (int nb = 0; nb < 2; nb++)
#pragma unroll
      for (int reg = 0; reg < 4; reg++) {
        int rg = tm * 128 + wm * 64 + mb * 16 + quad * 4 + reg;
        int col = tn * 64 + wn * 32 + nb * 16 + l15;
        Out[(size_t)rg * DMODEL + col] = acc[mb][nb][reg];
      }
}

extern "C" void kernel_launch(void* const* d_in, const int* in_sizes, int n_in,
                              void* d_out, int out_size, void* d_ws, size_t ws_size,
                              hipStream_t stream) {
  (void)in_sizes; (void)n_in; (void)out_size; (void)ws_size;
  const float* X  = (const float*)d_in[0];
  const int*   tp = (const int*)d_in[1];
  const float* Wq = (const float*)d_in[2];
  const float* Wk = (const float*)d_in[3];
  const float* Wv = (const float*)d_in[4];
  const float* Wo = (const float*)d_in[5];
  float* Out = (float*)d_out;

  short* Qb  = (short*)d_ws;           // 4M shorts each
  short* Kb  = Qb + 4194304;
  short* Vb  = Kb + 4194304;           // holds V^T (B,H,D,S)
  short* Ab  = Vb + 4194304;
  short* Xb  = Ab + 4194304;           // 4M
  short* Wqb = Xb + 4194304;           // 1M each
  short* Wkb = Wqb + 1048576;
  short* Wvb = Wkb + 1048576;
  short* Wob = Wvb + 1048576;
  float* ct  = (float*)(Wob + 1048576);
  float* st  = ct + SEQ * 32;

  precast_rope_kernel<<<dim3(4352), dim3(256), 0, stream>>>(
      X, Wq, Wk, Wv, Wo, tp, Xb, Wqb, Wkb, Wvb, Wob, ct, st);
  gemm_qkv_kernel<<<dim3(32, 24), dim3(256), 0, stream>>>(Xb, Wqb, Wkb, Wvb,
                                                          Qb, Kb, Vb, ct, st);
  attn_kernel<<<dim3(1024), dim3(256), 0, stream>>>(Qb, Kb, Vb, Ab);
  gemm_out_kernel<<<dim3(32, 16), dim3(256), 0, stream>>>(Ab, Wob, Out);
}